// Round 14
// baseline (147.411 us; speedup 1.0000x reference)
//
#include <hip/hip_runtime.h>
#include <hip/hip_bf16.h>
#include <stdint.h>

// Problem constants: B=2, S=2048, D=768, H=12, DK=64
typedef __attribute__((ext_vector_type(8))) short bf16x8;
typedef __attribute__((ext_vector_type(4))) short bf16x4;
typedef __attribute__((ext_vector_type(4))) float f32x4;
typedef __attribute__((ext_vector_type(16))) float f32x16;
typedef __attribute__((ext_vector_type(4))) unsigned short u16x4;

__device__ __forceinline__ unsigned short f2bf(float x) {
  union { __hip_bfloat16 h; unsigned short s; } u;
  u.h = __float2bfloat16(x);
  return u.s;
}
__device__ __forceinline__ unsigned int cvtpk(float lo, float hi) {
  unsigned int r;
  asm("v_cvt_pk_bf16_f32 %0, %1, %2" : "=v"(r) : "v"(lo), "v"(hi));
  return r;
}
// global -> LDS DMA, 16B per lane, dest = lds base + lane*16 (linear)
__device__ __forceinline__ void gll16(const unsigned short* g, unsigned short* l) {
  __builtin_amdgcn_global_load_lds(
      (const __attribute__((address_space(1))) unsigned int*)g,
      (__attribute__((address_space(3))) unsigned int*)l, 16, 0, 0);
}

// ---------------- mask pack v2: one thread per output u32 (32 mask ints) ----------------
__global__ __launch_bounds__(256) void maskpack2_kernel(const int* __restrict__ mask,
                                                        unsigned int* __restrict__ mp) {
  const int widx = blockIdx.x * 256 + threadIdx.x;  // 0..262143
  const int* src = mask + (size_t)widx * 32;
  unsigned int wbits = 0;
#pragma unroll
  for (int j = 0; j < 8; ++j) {
    int4 v = *(const int4*)(src + j * 4);
    wbits |= (v.x != 0 ? 1u : 0u) << (j * 4 + 0);
    wbits |= (v.y != 0 ? 1u : 0u) << (j * 4 + 1);
    wbits |= (v.z != 0 ? 1u : 0u) << (j * 4 + 2);
    wbits |= (v.w != 0 ? 1u : 0u) << (j * 4 + 3);
  }
  mp[widx] = wbits;
}

// ---------------- mask pack (ballot version, fallback path) ----------------
__global__ __launch_bounds__(256) void maskpack_kernel(const int* __restrict__ mask,
                                                       unsigned int* __restrict__ mp,
                                                       int total) {
  int i = blockIdx.x * blockDim.x + threadIdx.x;
  const int lane = threadIdx.x & 63;
  const int stride = gridDim.x * blockDim.x;
  for (; i < total; i += stride) {
    unsigned long long b = __ballot(mask[i] != 0);
    if (lane == 0)       mp[i >> 5] = (unsigned int)b;
    else if (lane == 32) mp[i >> 5] = (unsigned int)(b >> 32);
  }
}

// ---------------- precast: fp32 -> bf16 for Q,K,V (and W's; Wq scaled) ----------------
__global__ __launch_bounds__(256) void precast_kernel(
    const float* __restrict__ q, const float* __restrict__ k, const float* __restrict__ v,
    const float* __restrict__ wq, const float* __restrict__ wk, const float* __restrict__ wv,
    const float* __restrict__ wo,
    unsigned short* __restrict__ qb, unsigned short* __restrict__ kb, unsigned short* __restrict__ vb,
    unsigned short* __restrict__ wqb, unsigned short* __restrict__ wkb,
    unsigned short* __restrict__ wvb, unsigned short* __restrict__ wob) {
  const int U = 1474560;  // 8-elem units: 3*393216 (QKV) + 4*73728 (W)
  for (int u = blockIdx.x * blockDim.x + threadIdx.x; u < U; u += gridDim.x * blockDim.x) {
    const float* s; unsigned short* d; int r; float scale = 1.0f;
    if (u < 1179648) {
      int which = u / 393216; r = u - which * 393216;
      s = (which == 0) ? q : (which == 1) ? k : v;
      d = (which == 0) ? qb : (which == 1) ? kb : vb;
    } else {
      int u2 = u - 1179648; int which = u2 / 73728; r = u2 - which * 73728;
      s = (which == 0) ? wq : (which == 1) ? wk : (which == 2) ? wv : wo;
      d = (which == 0) ? wqb : (which == 1) ? wkb : (which == 2) ? wvb : wob;
      if (which == 0) scale = 0.18033688f;  // log2(e)/8 folded into Wq
    }
    float4 a = *(const float4*)&s[(size_t)r * 8];
    float4 b2 = *(const float4*)&s[(size_t)r * 8 + 4];
    uint4 o;
    o.x = cvtpk(a.x * scale, a.y * scale);
    o.y = cvtpk(a.z * scale, a.w * scale);
    o.z = cvtpk(b2.x * scale, b2.y * scale);
    o.w = cvtpk(b2.z * scale, b2.w * scale);
    *(uint4*)&d[(size_t)r * 8] = o;
  }
}

// ---------------- bf16 GEMM: 3-buffer rotation, 2-deep prefetch, counted vmcnt ----------------
// Tile 128x128, BK=32. Per-thread 4 gll16 per tile; vmcnt(4) after issuing tile
// t+2 leaves the newest 4 in flight while guaranteeing tile t+1 has landed
// (T4 counted-drain: loads get ~2 iterations to cover L2/HBM latency).
#define GEMM_BODY(AEXPR, BEXPR)                                                   \
  __shared__ unsigned short As[3][128][32];                                       \
  __shared__ unsigned short Bs[3][128][32];                                       \
  const int m0 = blockIdx.y * 128, n0 = blockIdx.x * 128;                         \
  const int t = threadIdx.x, lane = t & 63, w = t >> 6;                           \
  const int wr = w >> 1, wc = w & 1, fr = lane & 15, cl = lane >> 4;              \
  const int srl = lane >> 2, sph = lane & 3;                                      \
  f32x4 acc[4][4] = {};                                                           \
  auto ISSUE = [&](int kk, int buf) {                                             \
    _Pragma("unroll")                                                             \
    for (int i = 0; i < 2; ++i) {                                                 \
      const int row = i * 64 + w * 16 + srl;                                      \
      const int c = sph ^ ((row >> 1) & 3);                                       \
      gll16(AEXPR, &As[buf][i * 64 + w * 16][0]);                                 \
      gll16(BEXPR, &Bs[buf][i * 64 + w * 16][0]);                                 \
    }                                                                             \
  };                                                                              \
  ISSUE(0, 0);                                                                    \
  ISSUE(32, 1);                                                                   \
  asm volatile("s_waitcnt vmcnt(4)" ::: "memory");                                \
  __syncthreads();                                                                \
  for (int it = 0; it < 24; ++it) {                                               \
    const int buf = it - (it / 3) * 3;                                            \
    if (it < 22) {                                                                \
      const int nb = (it + 2) - ((it + 2) / 3) * 3;                               \
      ISSUE((it + 2) * 32, nb);                                                   \
    }                                                                             \
    bf16x8 af[4], bfr[4];                                                         \
    _Pragma("unroll")                                                             \
    for (int i = 0; i < 4; ++i) {                                                 \
      const int R = wr * 64 + i * 16 + fr;                                        \
      af[i] = *(const bf16x8*)&As[buf][R][(cl ^ ((R >> 1) & 3)) * 8];             \
    }                                                                             \
    _Pragma("unroll")                                                             \
    for (int j = 0; j < 4; ++j) {                                                 \
      const int R = wc * 64 + j * 16 + fr;                                        \
      bfr[j] = *(const bf16x8*)&Bs[buf][R][(cl ^ ((R >> 1) & 3)) * 8];            \
    }                                                                             \
    __builtin_amdgcn_s_setprio(1);                                                \
    _Pragma("unroll")                                                             \
    for (int i = 0; i < 4; ++i)                                                   \
      _Pragma("unroll")                                                           \
      for (int j = 0; j < 4; ++j)                                                 \
        acc[i][j] = __builtin_amdgcn_mfma_f32_16x16x32_bf16(af[i], bfr[j],        \
                                                            acc[i][j], 0, 0, 0); \
    __builtin_amdgcn_s_setprio(0);                                                \
    if (it < 22) asm volatile("s_waitcnt vmcnt(4)" ::: "memory");                 \
    else         asm volatile("s_waitcnt vmcnt(0)" ::: "memory");                 \
    __syncthreads();                                                              \
  }

// proj: A bf16 [4096][768] (Qb/Kb/Vb), B bf16 [768][768] (W*b); epilogue -> head layouts
__global__ __launch_bounds__(256) void proj_b16(
    const unsigned short* __restrict__ Qb, const unsigned short* __restrict__ Kb,
    const unsigned short* __restrict__ Vb,
    const unsigned short* __restrict__ Wqb, const unsigned short* __restrict__ Wkb,
    const unsigned short* __restrict__ Wvb,
    unsigned short* __restrict__ qo, unsigned short* __restrict__ ko,
    unsigned short* __restrict__ vo) {
  const int z = blockIdx.z;
  const unsigned short* A = (z == 0) ? Qb : (z == 1) ? Kb : Vb;
  const unsigned short* W = (z == 0) ? Wqb : (z == 1) ? Wkb : Wvb;
  GEMM_BODY(A + (size_t)(m0 + row) * 768 + kk + c * 8,
            W + (size_t)(n0 + row) * 768 + kk + c * 8)
  if (z == 2) {
    for (int i = 0; i < 4; ++i)
      for (int j = 0; j < 4; ++j) {
        int m = m0 + wr * 64 + i * 16 + (lane >> 4) * 4;
        int n = n0 + wc * 64 + j * 16 + fr;
        int b = m >> 11, s = m & 2047, hd = n >> 6, dk = n & 63;
        u16x4 pk;
        for (int r = 0; r < 4; ++r) pk[r] = f2bf(acc[i][j][r]);
        *(u16x4*)&vo[((size_t)(b * 12 + hd) * 64 + dk) * 2048 + s] = pk;
      }
  } else {
    unsigned short* O = (z == 0) ? qo : ko;
    for (int i = 0; i < 4; ++i)
      for (int j = 0; j < 4; ++j)
        for (int r = 0; r < 4; ++r) {
          int m = m0 + wr * 64 + i * 16 + (lane >> 4) * 4 + r;
          int n = n0 + wc * 64 + j * 16 + fr;
          int b = m >> 11, s = m & 2047, hd = n >> 6, dk = n & 63;
          O[((size_t)(b * 12 + hd) * 2048 + s) * 64 + dk] = f2bf(acc[i][j][r]);
        }
  }
}

// out: A = attn output bf16 [4096][768], B = Wob bf16; epilogue fp32
__global__ __launch_bounds__(256) void out_b16(
    const unsigned short* __restrict__ Ain, const unsigned short* __restrict__ Wob,
    float* __restrict__ Out) {
  GEMM_BODY(Ain + (size_t)(m0 + row) * 768 + kk + c * 8,
            Wob + (size_t)(n0 + row) * 768 + kk + c * 8)
  for (int i = 0; i < 4; ++i)
    for (int j = 0; j < 4; ++j)
      for (int r = 0; r < 4; ++r) {
        int m = m0 + wr * 64 + i * 16 + (lane >> 4) * 4 + r;
        int n = n0 + wc * 64 + j * 16 + fr;
        Out[(size_t)m * 768 + n] = acc[i][j][r];
      }
}

// ---------------- FALLBACK fp32-input GEMMs (used when ws too small) ----------------
__global__ __launch_bounds__(256) void proj_gemm(
    const float* __restrict__ Qi, const float* __restrict__ Ki, const float* __restrict__ Vi,
    const float* __restrict__ Wq, const float* __restrict__ Wk, const float* __restrict__ Wv,
    unsigned short* __restrict__ qo, unsigned short* __restrict__ ko, unsigned short* __restrict__ vo) {
  constexpr int LDT = 56;
  __shared__ unsigned short As[128][LDT];
  __shared__ unsigned short Bs[128][LDT];
  const int z = blockIdx.z;
  const float* A = (z == 0) ? Qi : (z == 1) ? Ki : Vi;
  const float* W = (z == 0) ? Wq : (z == 1) ? Wk : Wv;
  const int m0 = blockIdx.y * 128, n0 = blockIdx.x * 128;
  const int t = threadIdx.x, lane = t & 63, w = t >> 6;
  const int wr = w >> 1, wc = w & 1;
  const int fr = lane & 15, fg = (lane >> 4) * 8;
  const int srow = t >> 3, sseg = t & 7;
  f32x4 acc[4][4] = {};
  for (int kk = 0; kk < 768; kk += 32) {
    for (int pp = 0; pp < 4; ++pp) {
      int row = srow + pp * 32;
      float4 fa = *(const float4*)&A[(size_t)(m0 + row) * 768 + kk + sseg * 4];
      float4 fb = *(const float4*)&W[(size_t)(n0 + row) * 768 + kk + sseg * 4];
      bf16x4 pa = {(short)f2bf(fa.x), (short)f2bf(fa.y), (short)f2bf(fa.z), (short)f2bf(fa.w)};
      bf16x4 pb = {(short)f2bf(fb.x), (short)f2bf(fb.y), (short)f2bf(fb.z), (short)f2bf(fb.w)};
      *(bf16x4*)&As[row][sseg * 4] = pa;
      *(bf16x4*)&Bs[row][sseg * 4] = pb;
    }
    __syncthreads();
    bf16x8 af[4], bfr[4];
    for (int i = 0; i < 4; ++i) af[i]  = *(const bf16x8*)&As[wr * 64 + i * 16 + fr][fg];
    for (int i = 0; i < 4; ++i) bfr[i] = *(const bf16x8*)&Bs[wc * 64 + i * 16 + fr][fg];
    for (int i = 0; i < 4; ++i)
      for (int j = 0; j < 4; ++j)
        acc[i][j] = __builtin_amdgcn_mfma_f32_16x16x32_bf16(af[i], bfr[j], acc[i][j], 0, 0, 0);
    __syncthreads();
  }
  if (z == 2) {
    for (int i = 0; i < 4; ++i)
      for (int j = 0; j < 4; ++j) {
        int m = m0 + wr * 64 + i * 16 + (lane >> 4) * 4;
        int n = n0 + wc * 64 + j * 16 + fr;
        int b = m >> 11, s = m & 2047, hd = n >> 6, dk = n & 63;
        u16x4 pk;
        for (int r = 0; r < 4; ++r) pk[r] = f2bf(acc[i][j][r]);
        *(u16x4*)&vo[((size_t)(b * 12 + hd) * 64 + dk) * 2048 + s] = pk;
      }
  } else {
    unsigned short* O = (z == 0) ? qo : ko;
    const float scale = (z == 0) ? 0.18033688f : 1.0f;
    for (int i = 0; i < 4; ++i)
      for (int j = 0; j < 4; ++j)
        for (int r = 0; r < 4; ++r) {
          int m = m0 + wr * 64 + i * 16 + (lane >> 4) * 4 + r;
          int n = n0 + wc * 64 + j * 16 + fr;
          int b = m >> 11, s = m & 2047, hd = n >> 6, dk = n & 63;
          O[((size_t)(b * 12 + hd) * 2048 + s) * 64 + dk] = f2bf(acc[i][j][r] * scale);
        }
  }
}

__global__ __launch_bounds__(256) void out_gemm(
    const unsigned short* __restrict__ Ain, const float* __restrict__ W,
    float* __restrict__ Out) {
  constexpr int LDT = 56;
  __shared__ unsigned short As[128][LDT];
  __shared__ unsigned short Bs[128][LDT];
  const int m0 = blockIdx.y * 128, n0 = blockIdx.x * 128;
  const int t = threadIdx.x, lane = t & 63, w = t >> 6;
  const int wr = w >> 1, wc = w & 1;
  const int fr = lane & 15, fg = (lane >> 4) * 8;
  f32x4 acc[4][4] = {};
  for (int kk = 0; kk < 768; kk += 32) {
    {
      int row = t >> 2, seg = t & 3;
      for (int pp = 0; pp < 2; ++pp) {
        bf16x8 va = *(const bf16x8*)&Ain[(size_t)(m0 + row + pp * 64) * 768 + kk + seg * 8];
        *(bf16x8*)&As[row + pp * 64][seg * 8] = va;
      }
      int row2 = t >> 3, seg2 = t & 7;
      for (int pp = 0; pp < 4; ++pp) {
        float4 fb = *(const float4*)&W[(size_t)(n0 + row2 + pp * 32) * 768 + kk + seg2 * 4];
        bf16x4 pb = {(short)f2bf(fb.x), (short)f2bf(fb.y), (short)f2bf(fb.z), (short)f2bf(fb.w)};
        *(bf16x4*)&Bs[row2 + pp * 32][seg2 * 4] = pb;
      }
    }
    __syncthreads();
    bf16x8 af[4], bfr[4];
    for (int i = 0; i < 4; ++i) af[i]  = *(const bf16x8*)&As[wr * 64 + i * 16 + fr][fg];
    for (int i = 0; i < 4; ++i) bfr[i] = *(const bf16x8*)&Bs[wc * 64 + i * 16 + fr][fg];
    for (int i = 0; i < 4; ++i)
      for (int j = 0; j < 4; ++j)
        acc[i][j] = __builtin_amdgcn_mfma_f32_16x16x32_bf16(af[i], bfr[j], acc[i][j], 0, 0, 0);
    __syncthreads();
  }
  for (int i = 0; i < 4; ++i)
    for (int j = 0; j < 4; ++j)
      for (int r = 0; r < 4; ++r) {
        int m = m0 + wr * 64 + i * 16 + (lane >> 4) * 4 + r;
        int n = n0 + wc * 64 + j * 16 + fr;
        Out[(size_t)m * 768 + n] = acc[i][j][r];
      }
}

// ---------------- flash attention (VERBATIM round-6 82.5µs configuration) ----------------
// 8 waves = 2 q-waves x 4 key-splits, 32-key tiles, K+V LDS double-buffered via
// global_load_lds; online softmax with defer-rescale; Sm/Sl merge epilogue.
// Round-8 lesson: the fixed-max variant recompiled to 72 VGPR (>64 cliff, m69)
// and lost a third of occupancy — keep this exact source.
__global__ __launch_bounds__(512) void attn_kernel(
    const unsigned short* __restrict__ qh, const unsigned short* __restrict__ kh,
    const unsigned short* __restrict__ vh, const unsigned int* __restrict__ mp,
    unsigned short* __restrict__ ao) {
  __shared__ union LdsU {
    struct {
      unsigned short K[2][4][32][64];  // [buf][sp][key][dk], chunk ^= (key&7)
      unsigned short V[2][4][64][32];  // [buf][sp][dk][key], chunk ^= ((dk>>1)&3)
    } st;
    float M[8][32][64];                // split-merge overlay (after loop only)
  } lds;
  __shared__ float Sm[8][64];
  __shared__ float Sl[8][64];
  const int t = threadIdx.x, lane = t & 63, w = t >> 6;
  const int wq = w & 1, sp = w >> 1;  // q-half, key-split
  // XCD swizzle: 768 blocks = 8 XCDs x (3 heads x 32 q-blocks)
  const int bid = blockIdx.x;
  const int xcd = bid & 7, idx = bid >> 3;
  const int bh = xcd * 3 + (idx >> 5);
  const int qb = idx & 31;
  const int bb = bh / 12, hh = bh % 12;
  const int qc = lane & 31, h = lane >> 5;
  const int q = qb * 64 + wq * 32 + qc;
  // Q B-fragments (pre-scaled by log2e/8): B[k][q], k = kc*16 + h*8 + j
  const unsigned short* qrow = qh + ((size_t)bh * 2048 + q) * 64;
  bf16x8 bq[4];
#pragma unroll
  for (int kc = 0; kc < 4; ++kc) bq[kc] = *(const bf16x8*)(qrow + kc * 16 + h * 8);
  const unsigned int* mrow = mp + ((size_t)bb * 2048 + q) * 64 + sp * 16;
  const unsigned short* kgb = kh + (size_t)bh * 2048 * 64;
  const unsigned short* vgb = vh + (size_t)bh * 64 * 2048;  // V^T: [64][2048]
  f32x16 acc0 = {}, acc1 = {};
  float l_run = 0.f;
  float m_run = -1e30f;
  const int KT0 = sp * 512;
  const int krow = lane >> 3, ksch = (lane & 7) ^ (lane >> 3);        // K staging
  const int vrow = lane >> 2, vsch = (lane & 3) ^ ((lane >> 3) & 3);  // V staging
  auto ISSUE = [&](int it2, int b2) {
    const int KT = KT0 + it2 * 32;
    unsigned short* kd = &lds.st.K[b2][sp][0][0];
    unsigned short* vd = &lds.st.V[b2][sp][0][0];
#pragma unroll
    for (int c2 = 0; c2 < 2; ++c2) {
      const int c = 2 * wq + c2;
      gll16(kgb + (size_t)(KT + c * 8 + krow) * 64 + ksch * 8, kd + c * 512);
    }
#pragma unroll
    for (int c2 = 0; c2 < 2; ++c2) {
      const int c = 2 * wq + c2;
      gll16(vgb + (size_t)(c * 16 + vrow) * 2048 + KT + vsch * 8, vd + c * 512);
    }
  };
  ISSUE(0, 0);
#pragma unroll 2
  for (int it = 0; it < 16; ++it) {
    const int b = it & 1;
    asm volatile("s_waitcnt vmcnt(0)" ::: "memory");
    __syncthreads();
    if (it < 15) ISSUE(it + 1, b ^ 1);
    const unsigned int m32 = mrow[it];
    // ---- K A-frags (swizzled ds_read) ----
    bf16x8 ka[4];
#pragma unroll
    for (int kc = 0; kc < 4; ++kc)
      ka[kc] = *(const bf16x8*)&lds.st.K[b][sp][qc][((kc * 2 + h) ^ (qc & 7)) * 8];
    f32x16 sc = {};
    __builtin_amdgcn_s_setprio(1);
#pragma unroll
    for (int kc = 0; kc < 4; ++kc)
      sc = __builtin_amdgcn_mfma_f32_32x32x16_bf16(ka[kc], bq[kc], sc, 0, 0, 0);
    __builtin_amdgcn_s_setprio(0);
    // ---- V A-frags (latency hidden under softmax) ----
    bf16x8 va0[2], va1[2];
#pragma unroll
    for (int ks = 0; ks < 2; ++ks) {
      const int cs = ((ks * 2 + h) ^ ((qc >> 1) & 3)) * 8;
      va0[ks] = *(const bf16x8*)&lds.st.V[b][sp][qc][cs];
      va1[ks] = *(const bf16x8*)&lds.st.V[b][sp][32 + qc][cs];
    }
    // ---- mask (key bit = (r&3)+8*(r>>2)+4h) ----
    const unsigned int wsh = m32 >> (4 * h);
#pragma unroll
    for (int r = 0; r < 16; ++r) {
      const int sh = (r & 3) + 8 * (r >> 2);
      sc[r] = ((wsh >> sh) & 1u) ? sc[r] : -3.0e38f;
    }
    // ---- tile max (balanced tree) ----
    float mA0 = fmaxf(fmaxf(sc[0], sc[4]), fmaxf(sc[8], sc[12]));
    float mA1 = fmaxf(fmaxf(sc[1], sc[5]), fmaxf(sc[9], sc[13]));
    float mA2 = fmaxf(fmaxf(sc[2], sc[6]), fmaxf(sc[10], sc[14]));
    float mA3 = fmaxf(fmaxf(sc[3], sc[7]), fmaxf(sc[11], sc[15]));
    float m1 = fmaxf(fmaxf(mA0, mA1), fmaxf(mA2, mA3));
    float tmax = fmaxf(m1, __shfl_xor(m1, 32, 64));
    // ---- T13 defer-rescale (log2 domain) ----
    if (__any(tmax > m_run + 8.0f)) {
      float mnew = fmaxf(m_run, tmax);
      float scl = exp2f(m_run - mnew);
      m_run = mnew;
      l_run *= scl;
#pragma unroll
      for (int e = 0; e < 16; ++e) { acc0[e] *= scl; acc1[e] *= scl; }
    }
    // ---- p = exp2(s - m), sum tree ----
#pragma unroll
    for (int r = 0; r < 16; ++r) sc[r] = exp2f(sc[r] - m_run);
    float sA0 = (sc[0] + sc[4]) + (sc[8] + sc[12]);
    float sA1 = (sc[1] + sc[5]) + (sc[9] + sc[13]);
    float sA2 = (sc[2] + sc[6]) + (sc[10] + sc[14]);
    float sA3 = (sc[3] + sc[7]) + (sc[11] + sc[15]);
    float s1 = (sA0 + sA1) + (sA2 + sA3);
    l_run += s1 + __shfl_xor(s1, 32, 64);
    // ---- PV: O^T += V^T . P^T (cvt_pk + permlane32_swap redistribution) ----
    __builtin_amdgcn_s_setprio(1);
#define PVQ(P, OFF, A0, A1) { \
    unsigned int a0 = cvtpk(P[OFF + 0], P[OFF + 1]), a1 = cvtpk(P[OFF + 2], P[OFF + 3]); \
    unsigned int b0 = cvtpk(P[OFF + 4], P[OFF + 5]), b1 = cvtpk(P[OFF + 6], P[OFF + 7]); \
    asm("v_permlane32_swap_b32 %0, %1" : "+v"(a0), "+v"(b0)); \
    asm("v_permlane32_swap_b32 %0, %1" : "+v"(a1), "+v"(b1)); \
    union { unsigned int u[4]; bf16x8 v; } bfu; \
    bfu.u[0] = a0; bfu.u[1] = a1; bfu.u[2] = b0; bfu.u[3] = b1; \
    acc0 = __builtin_amdgcn_mfma_f32_32x32x16_bf16(A0, bfu.v, acc0, 0, 0, 0); \
    acc1 = __builtin_amdgcn_mfma_f32_32x32x16_bf16(A1, bfu.v, acc1, 0, 0, 0); }
    PVQ(sc, 0, va0[0], va1[0]);
    PVQ(sc, 8, va0[1], va1[1]);
#undef PVQ
    __builtin_amdgcn_s_setprio(0);
  }
  __syncthreads();  // staging reads done before merge overlay writes
  // ---- merge 4 split partials through LDS ----
  Sm[w][lane] = m_run;
  Sl[w][lane] = l_run;
#pragma unroll
  for (int e = 0; e < 16; ++e) lds.M[w][e][lane] = acc0[e];
#pragma unroll
  for (int e = 0; e < 16; ++e) lds.M[w][16 + e][lane] = acc1[e];
  __syncthreads();
  float pm0 = Sm[wq][lane],     pm1 = Sm[2 + wq][lane];
  float pm2 = Sm[4 + wq][lane], pm3 = Sm[6 + wq][lane];
  float M = fmaxf(fmaxf(pm0, pm1), fmaxf(pm2, pm3));
  float w0 = exp2f(pm0 - M), w1 = exp2f(pm1 - M), w2 = exp2f(pm2 - M), w3 = exp2f(pm3 - M);
  float L = Sl[wq][lane] * w0 + Sl[2 + wq][lane] * w1 +
            Sl[4 + wq][lane] * w2 + Sl[6 + wq][lane] * w3;
  float inv = (L > 0.f) ? 1.0f / L : 0.f;
  unsigned short* orow = ao + ((size_t)bb * 2048 + q) * 768 + hh * 64;
#pragma unroll
  for (int g = 0; g < 2; ++g) {
    const int e0 = sp * 8 + g * 4;
    const int base = (e0 >= 16) ? 32 : 0;
    const int er0 = e0 & 15;
    const int d0 = base + 8 * (er0 >> 2) + 4 * h;
    u16x4 pk4;
#pragma unroll
    for (int j = 0; j < 4; ++j) {
      float v = (lds.M[wq][e0 + j][lane] * w0 + lds.M[2 + wq][e0 + j][lane] * w1 +
                 lds.M[4 + wq][e0 + j][lane] * w2 + lds.M[6 + wq][e0 + j][lane] * w3) * inv;
      pk4[j] = f2bf(v);
    }
    *(u16x4*)&orow[d0] = pk4;
  }
}

extern "C" void kernel_launch(void* const* d_in, const int* in_sizes, int n_in,
                              void* d_out, int out_size, void* d_ws, size_t ws_size,
                              hipStream_t stream) {
  const float* Q  = (const float*)d_in[0];
  const float* K  = (const float*)d_in[1];
  const float* V  = (const float*)d_in[2];
  const int*   mask = (const int*)d_in[3];
  const float* WQ = (const float*)d_in[4];
  const float* WK = (const float*)d_in[5];
  const float* WV = (const float*)d_in[6];
  const float* WO = (const float*)d_in[7];
  float* out = (float*)d_out;
  char* ws = (char*)d_ws;

  const size_t NEED = 43515904ull;
  if (ws_size >= NEED) {
    unsigned short* qh  = (unsigned short*)(ws + 0);
    unsigned short* kh  = (unsigned short*)(ws + 6291456);
    unsigned short* vh  = (unsigned short*)(ws + 12582912);
    unsigned int*   mp  = (unsigned int*)(ws + 18874368);
    unsigned short* Qb  = (unsigned short*)(ws + 19922944);  // aliased by ao after proj
    unsigned short* ao  = Qb;
    unsigned short* Kb  = (unsigned short*)(ws + 26214400);
    unsigned short* Vb  = (unsigned short*)(ws + 32505856);
    unsigned short* Wqb = (unsigned short*)(ws + 38797312);
    unsigned short* Wkb = (unsigned short*)(ws + 39976960);
    unsigned short* Wvb = (unsigned short*)(ws + 41156608);
    unsigned short* Wob = (unsigned short*)(ws + 42336256);
    maskpack2_kernel<<<dim3(1024), 256, 0, stream>>>(mask, mp);
    precast_kernel<<<dim3(2880), 256, 0, stream>>>(Q, K, V, WQ, WK, WV, WO,
                                                   Qb, Kb, Vb, Wqb, Wkb, Wvb, Wob);
    proj_b16<<<dim3(6, 32, 3), 256, 0, stream>>>(Qb, Kb, Vb, Wqb, Wkb, Wvb, qh, kh, vh);
    attn_kernel<<<dim3(768), 512, 0, stream>>>(qh, kh, vh, mp, ao);
    out_b16<<<dim3(6, 32), 256, 0, stream>>>(ao, Wob, out);
  } else {
    unsigned short* qh = (unsigned short*)(ws + 0);
    unsigned short* kh = (unsigned short*)(ws + 6291456);
    unsigned short* vh = (unsigned short*)(ws + 12582912);
    unsigned short* ao = (unsigned short*)(ws + 18874368);
    unsigned int*   mp = (unsigned int*)(ws + 25165824);
    maskpack_kernel<<<dim3(2048), 256, 0, stream>>>(mask, mp, 2 * 2048 * 2048);
    proj_gemm<<<dim3(6, 32, 3), 256, 0, stream>>>(Q, K, V, WQ, WK, WV, qh, kh, vh);
    attn_kernel<<<dim3(768), 512, 0, stream>>>(qh, kh, vh, mp, ao);
    out_gemm<<<dim3(6, 32), 256, 0, stream>>>(ao, WO, out);
  }
}

// Round 15
// 144.774 us; speedup vs baseline: 1.0182x; 1.0182x over previous
//
#include <hip/hip_runtime.h>
#include <hip/hip_bf16.h>
#include <stdint.h>

// Problem constants: B=2, S=2048, D=768, H=12, DK=64
typedef __attribute__((ext_vector_type(8))) short bf16x8;
typedef __attribute__((ext_vector_type(4))) short bf16x4;
typedef __attribute__((ext_vector_type(4))) float f32x4;
typedef __attribute__((ext_vector_type(16))) float f32x16;
typedef __attribute__((ext_vector_type(4))) unsigned short u16x4;

__device__ __forceinline__ unsigned short f2bf(float x) {
  union { __hip_bfloat16 h; unsigned short s; } u;
  u.h = __float2bfloat16(x);
  return u.s;
}
__device__ __forceinline__ unsigned int cvtpk(float lo, float hi) {
  unsigned int r;
  asm("v_cvt_pk_bf16_f32 %0, %1, %2" : "=v"(r) : "v"(lo), "v"(hi));
  return r;
}
// global -> LDS DMA, 16B per lane, dest = lds base + lane*16 (linear)
__device__ __forceinline__ void gll16(const unsigned short* g, unsigned short* l) {
  __builtin_amdgcn_global_load_lds(
      (const __attribute__((address_space(1))) unsigned int*)g,
      (__attribute__((address_space(3))) unsigned int*)l, 16, 0, 0);
}

// ---------------- fused prep: maskpack2 (blocks 0..1023) + precast (blocks 1024..3903) ----------------
__global__ __launch_bounds__(256) void prep_kernel(
    const int* __restrict__ mask, unsigned int* __restrict__ mp,
    const float* __restrict__ q, const float* __restrict__ k, const float* __restrict__ v,
    const float* __restrict__ wq, const float* __restrict__ wk, const float* __restrict__ wv,
    const float* __restrict__ wo,
    unsigned short* __restrict__ qb, unsigned short* __restrict__ kb, unsigned short* __restrict__ vb,
    unsigned short* __restrict__ wqb, unsigned short* __restrict__ wkb,
    unsigned short* __restrict__ wvb, unsigned short* __restrict__ wob) {
  if (blockIdx.x < 1024) {
    // mask pack: one thread per output u32 (32 mask ints); int4 loads, in-lane packing
    const int widx = blockIdx.x * 256 + threadIdx.x;  // 0..262143
    const int* src = mask + (size_t)widx * 32;
    unsigned int wbits = 0;
#pragma unroll
    for (int j = 0; j < 8; ++j) {
      int4 vv = *(const int4*)(src + j * 4);
      wbits |= (vv.x != 0 ? 1u : 0u) << (j * 4 + 0);
      wbits |= (vv.y != 0 ? 1u : 0u) << (j * 4 + 1);
      wbits |= (vv.z != 0 ? 1u : 0u) << (j * 4 + 2);
      wbits |= (vv.w != 0 ? 1u : 0u) << (j * 4 + 3);
    }
    mp[widx] = wbits;
  } else {
    // precast fp32 -> bf16 (Wq scaled by log2(e)/8)
    const int U = 1474560;  // 8-elem units: 3*393216 (QKV) + 4*73728 (W)
    const int stride = 2880 * 256;
    for (int u = (blockIdx.x - 1024) * 256 + threadIdx.x; u < U; u += stride) {
      const float* s; unsigned short* d; int r; float scale = 1.0f;
      if (u < 1179648) {
        int which = u / 393216; r = u - which * 393216;
        s = (which == 0) ? q : (which == 1) ? k : v;
        d = (which == 0) ? qb : (which == 1) ? kb : vb;
      } else {
        int u2 = u - 1179648; int which = u2 / 73728; r = u2 - which * 73728;
        s = (which == 0) ? wq : (which == 1) ? wk : (which == 2) ? wv : wo;
        d = (which == 0) ? wqb : (which == 1) ? wkb : (which == 2) ? wvb : wob;
        if (which == 0) scale = 0.18033688f;
      }
      float4 a = *(const float4*)&s[(size_t)r * 8];
      float4 b2 = *(const float4*)&s[(size_t)r * 8 + 4];
      uint4 o;
      o.x = cvtpk(a.x * scale, a.y * scale);
      o.y = cvtpk(a.z * scale, a.w * scale);
      o.z = cvtpk(b2.x * scale, b2.y * scale);
      o.w = cvtpk(b2.z * scale, b2.w * scale);
      *(uint4*)&d[(size_t)r * 8] = o;
    }
  }
}

// ---------------- mask pack (ballot version, fallback path) ----------------
__global__ __launch_bounds__(256) void maskpack_kernel(const int* __restrict__ mask,
                                                       unsigned int* __restrict__ mp,
                                                       int total) {
  int i = blockIdx.x * blockDim.x + threadIdx.x;
  const int lane = threadIdx.x & 63;
  const int stride = gridDim.x * blockDim.x;
  for (; i < total; i += stride) {
    unsigned long long b = __ballot(mask[i] != 0);
    if (lane == 0)       mp[i >> 5] = (unsigned int)b;
    else if (lane == 32) mp[i >> 5] = (unsigned int)(b >> 32);
  }
}

// ---------------- bf16 GEMM: 3-buffer rotation, 2-deep prefetch, counted vmcnt ----------------
#define GEMM_BODY(AEXPR, BEXPR)                                                   \
  __shared__ unsigned short As[3][128][32];                                       \
  __shared__ unsigned short Bs[3][128][32];                                       \
  const int m0 = blockIdx.y * 128, n0 = blockIdx.x * 128;                         \
  const int t = threadIdx.x, lane = t & 63, w = t >> 6;                           \
  const int wr = w >> 1, wc = w & 1, fr = lane & 15, cl = lane >> 4;              \
  const int srl = lane >> 2, sph = lane & 3;                                      \
  f32x4 acc[4][4] = {};                                                           \
  auto ISSUE = [&](int kk, int buf) {                                             \
    _Pragma("unroll")                                                             \
    for (int i = 0; i < 2; ++i) {                                                 \
      const int row = i * 64 + w * 16 + srl;                                      \
      const int c = sph ^ ((row >> 1) & 3);                                       \
      gll16(AEXPR, &As[buf][i * 64 + w * 16][0]);                                 \
      gll16(BEXPR, &Bs[buf][i * 64 + w * 16][0]);                                 \
    }                                                                             \
  };                                                                              \
  ISSUE(0, 0);                                                                    \
  ISSUE(32, 1);                                                                   \
  asm volatile("s_waitcnt vmcnt(4)" ::: "memory");                                \
  __syncthreads();                                                                \
  for (int it = 0; it < 24; ++it) {                                               \
    const int buf = it - (it / 3) * 3;                                            \
    if (it < 22) {                                                                \
      const int nb = (it + 2) - ((it + 2) / 3) * 3;                               \
      ISSUE((it + 2) * 32, nb);                                                   \
    }                                                                             \
    bf16x8 af[4], bfr[4];                                                         \
    _Pragma("unroll")                                                             \
    for (int i = 0; i < 4; ++i) {                                                 \
      const int R = wr * 64 + i * 16 + fr;                                        \
      af[i] = *(const bf16x8*)&As[buf][R][(cl ^ ((R >> 1) & 3)) * 8];             \
    }                                                                             \
    _Pragma("unroll")                                                             \
    for (int j = 0; j < 4; ++j) {                                                 \
      const int R = wc * 64 + j * 16 + fr;                                        \
      bfr[j] = *(const bf16x8*)&Bs[buf][R][(cl ^ ((R >> 1) & 3)) * 8];            \
    }                                                                             \
    __builtin_amdgcn_s_setprio(1);                                                \
    _Pragma("unroll")                                                             \
    for (int i = 0; i < 4; ++i)                                                   \
      _Pragma("unroll")                                                           \
      for (int j = 0; j < 4; ++j)                                                 \
        acc[i][j] = __builtin_amdgcn_mfma_f32_16x16x32_bf16(af[i], bfr[j],        \
                                                            acc[i][j], 0, 0, 0); \
    __builtin_amdgcn_s_setprio(0);                                                \
    if (it < 22) asm volatile("s_waitcnt vmcnt(4)" ::: "memory");                 \
    else         asm volatile("s_waitcnt vmcnt(0)" ::: "memory");                 \
    __syncthreads();                                                              \
  }

// proj: A bf16 [4096][768] (Qb/Kb/Vb), B bf16 [768][768] (W*b); epilogue -> head layouts
__global__ __launch_bounds__(256) void proj_b16(
    const unsigned short* __restrict__ Qb, const unsigned short* __restrict__ Kb,
    const unsigned short* __restrict__ Vb,
    const unsigned short* __restrict__ Wqb, const unsigned short* __restrict__ Wkb,
    const unsigned short* __restrict__ Wvb,
    unsigned short* __restrict__ qo, unsigned short* __restrict__ ko,
    unsigned short* __restrict__ vo) {
  const int z = blockIdx.z;
  const unsigned short* A = (z == 0) ? Qb : (z == 1) ? Kb : Vb;
  const unsigned short* W = (z == 0) ? Wqb : (z == 1) ? Wkb : Wvb;
  GEMM_BODY(A + (size_t)(m0 + row) * 768 + kk + c * 8,
            W + (size_t)(n0 + row) * 768 + kk + c * 8)
  if (z == 2) {
    for (int i = 0; i < 4; ++i)
      for (int j = 0; j < 4; ++j) {
        int m = m0 + wr * 64 + i * 16 + (lane >> 4) * 4;
        int n = n0 + wc * 64 + j * 16 + fr;
        int b = m >> 11, s = m & 2047, hd = n >> 6, dk = n & 63;
        u16x4 pk;
        for (int r = 0; r < 4; ++r) pk[r] = f2bf(acc[i][j][r]);
        *(u16x4*)&vo[((size_t)(b * 12 + hd) * 64 + dk) * 2048 + s] = pk;
      }
  } else {
    unsigned short* O = (z == 0) ? qo : ko;
    for (int i = 0; i < 4; ++i)
      for (int j = 0; j < 4; ++j)
        for (int r = 0; r < 4; ++r) {
          int m = m0 + wr * 64 + i * 16 + (lane >> 4) * 4 + r;
          int n = n0 + wc * 64 + j * 16 + fr;
          int b = m >> 11, s = m & 2047, hd = n >> 6, dk = n & 63;
          O[((size_t)(b * 12 + hd) * 2048 + s) * 64 + dk] = f2bf(acc[i][j][r]);
        }
  }
}

// out: A = attn output bf16 [4096][768], B = Wob bf16; epilogue fp32
__global__ __launch_bounds__(256) void out_b16(
    const unsigned short* __restrict__ Ain, const unsigned short* __restrict__ Wob,
    float* __restrict__ Out) {
  GEMM_BODY(Ain + (size_t)(m0 + row) * 768 + kk + c * 8,
            Wob + (size_t)(n0 + row) * 768 + kk + c * 8)
  for (int i = 0; i < 4; ++i)
    for (int j = 0; j < 4; ++j)
      for (int r = 0; r < 4; ++r) {
        int m = m0 + wr * 64 + i * 16 + (lane >> 4) * 4 + r;
        int n = n0 + wc * 64 + j * 16 + fr;
        Out[(size_t)m * 768 + n] = acc[i][j][r];
      }
}

// ---------------- FALLBACK fp32-input GEMMs (used when ws too small) ----------------
__global__ __launch_bounds__(256) void proj_gemm(
    const float* __restrict__ Qi, const float* __restrict__ Ki, const float* __restrict__ Vi,
    const float* __restrict__ Wq, const float* __restrict__ Wk, const float* __restrict__ Wv,
    unsigned short* __restrict__ qo, unsigned short* __restrict__ ko, unsigned short* __restrict__ vo) {
  constexpr int LDT = 56;
  __shared__ unsigned short As[128][LDT];
  __shared__ unsigned short Bs[128][LDT];
  const int z = blockIdx.z;
  const float* A = (z == 0) ? Qi : (z == 1) ? Ki : Vi;
  const float* W = (z == 0) ? Wq : (z == 1) ? Wk : Wv;
  const int m0 = blockIdx.y * 128, n0 = blockIdx.x * 128;
  const int t = threadIdx.x, lane = t & 63, w = t >> 6;
  const int wr = w >> 1, wc = w & 1;
  const int fr = lane & 15, fg = (lane >> 4) * 8;
  const int srow = t >> 3, sseg = t & 7;
  f32x4 acc[4][4] = {};
  for (int kk = 0; kk < 768; kk += 32) {
    for (int pp = 0; pp < 4; ++pp) {
      int row = srow + pp * 32;
      float4 fa = *(const float4*)&A[(size_t)(m0 + row) * 768 + kk + sseg * 4];
      float4 fb = *(const float4*)&W[(size_t)(n0 + row) * 768 + kk + sseg * 4];
      bf16x4 pa = {(short)f2bf(fa.x), (short)f2bf(fa.y), (short)f2bf(fa.z), (short)f2bf(fa.w)};
      bf16x4 pb = {(short)f2bf(fb.x), (short)f2bf(fb.y), (short)f2bf(fb.z), (short)f2bf(fb.w)};
      *(bf16x4*)&As[row][sseg * 4] = pa;
      *(bf16x4*)&Bs[row][sseg * 4] = pb;
    }
    __syncthreads();
    bf16x8 af[4], bfr[4];
    for (int i = 0; i < 4; ++i) af[i]  = *(const bf16x8*)&As[wr * 64 + i * 16 + fr][fg];
    for (int i = 0; i < 4; ++i) bfr[i] = *(const bf16x8*)&Bs[wc * 64 + i * 16 + fr][fg];
    for (int i = 0; i < 4; ++i)
      for (int j = 0; j < 4; ++j)
        acc[i][j] = __builtin_amdgcn_mfma_f32_16x16x32_bf16(af[i], bfr[j], acc[i][j], 0, 0, 0);
    __syncthreads();
  }
  if (z == 2) {
    for (int i = 0; i < 4; ++i)
      for (int j = 0; j < 4; ++j) {
        int m = m0 + wr * 64 + i * 16 + (lane >> 4) * 4;
        int n = n0 + wc * 64 + j * 16 + fr;
        int b = m >> 11, s = m & 2047, hd = n >> 6, dk = n & 63;
        u16x4 pk;
        for (int r = 0; r < 4; ++r) pk[r] = f2bf(acc[i][j][r]);
        *(u16x4*)&vo[((size_t)(b * 12 + hd) * 64 + dk) * 2048 + s] = pk;
      }
  } else {
    unsigned short* O = (z == 0) ? qo : ko;
    const float scale = (z == 0) ? 0.18033688f : 1.0f;
    for (int i = 0; i < 4; ++i)
      for (int j = 0; j < 4; ++j)
        for (int r = 0; r < 4; ++r) {
          int m = m0 + wr * 64 + i * 16 + (lane >> 4) * 4 + r;
          int n = n0 + wc * 64 + j * 16 + fr;
          int b = m >> 11, s = m & 2047, hd = n >> 6, dk = n & 63;
          O[((size_t)(b * 12 + hd) * 2048 + s) * 64 + dk] = f2bf(acc[i][j][r] * scale);
        }
  }
}

__global__ __launch_bounds__(256) void out_gemm(
    const unsigned short* __restrict__ Ain, const float* __restrict__ W,
    float* __restrict__ Out) {
  constexpr int LDT = 56;
  __shared__ unsigned short As[128][LDT];
  __shared__ unsigned short Bs[128][LDT];
  const int m0 = blockIdx.y * 128, n0 = blockIdx.x * 128;
  const int t = threadIdx.x, lane = t & 63, w = t >> 6;
  const int wr = w >> 1, wc = w & 1;
  const int fr = lane & 15, fg = (lane >> 4) * 8;
  f32x4 acc[4][4] = {};
  for (int kk = 0; kk < 768; kk += 32) {
    {
      int row = t >> 2, seg = t & 3;
      for (int pp = 0; pp < 2; ++pp) {
        bf16x8 va = *(const bf16x8*)&Ain[(size_t)(m0 + row + pp * 64) * 768 + kk + seg * 8];
        *(bf16x8*)&As[row + pp * 64][seg * 8] = va;
      }
      int row2 = t >> 3, seg2 = t & 7;
      for (int pp = 0; pp < 4; ++pp) {
        float4 fb = *(const float4*)&W[(size_t)(n0 + row2 + pp * 32) * 768 + kk + seg2 * 4];
        bf16x4 pb = {(short)f2bf(fb.x), (short)f2bf(fb.y), (short)f2bf(fb.z), (short)f2bf(fb.w)};
        *(bf16x4*)&Bs[row2 + pp * 32][seg2 * 4] = pb;
      }
    }
    __syncthreads();
    bf16x8 af[4], bfr[4];
    for (int i = 0; i < 4; ++i) af[i]  = *(const bf16x8*)&As[wr * 64 + i * 16 + fr][fg];
    for (int i = 0; i < 4; ++i) bfr[i] = *(const bf16x8*)&Bs[wc * 64 + i * 16 + fr][fg];
    for (int i = 0; i < 4; ++i)
      for (int j = 0; j < 4; ++j)
        acc[i][j] = __builtin_amdgcn_mfma_f32_16x16x32_bf16(af[i], bfr[j], acc[i][j], 0, 0, 0);
    __syncthreads();
  }
  for (int i = 0; i < 4; ++i)
    for (int j = 0; j < 4; ++j)
      for (int r = 0; r < 4; ++r) {
        int m = m0 + wr * 64 + i * 16 + (lane >> 4) * 4 + r;
        int n = n0 + wc * 64 + j * 16 + fr;
        Out[(size_t)m * 768 + n] = acc[i][j][r];
      }
}

// ---------------- flash attention (VERBATIM round-6 82.5µs configuration) ----------------
// 8 waves = 2 q-waves x 4 key-splits, 32-key tiles, K+V LDS double-buffered via
// global_load_lds; online softmax with defer-rescale; Sm/Sl merge epilogue.
// Round-8 lesson: the fixed-max variant recompiled to 72 VGPR (>64 cliff, m69)
// and lost a third of occupancy — keep this exact source.
__global__ __launch_bounds__(512) void attn_kernel(
    const unsigned short* __restrict__ qh, const unsigned short* __restrict__ kh,
    const unsigned short* __restrict__ vh, const unsigned int* __restrict__ mp,
    unsigned short* __restrict__ ao) {
  __shared__ union LdsU {
    struct {
      unsigned short K[2][4][32][64];  // [buf][sp][key][dk], chunk ^= (key&7)
      unsigned short V[2][4][64][32];  // [buf][sp][dk][key], chunk ^= ((dk>>1)&3)
    } st;
    float M[8][32][64];                // split-merge overlay (after loop only)
  } lds;
  __shared__ float Sm[8][64];
  __shared__ float Sl[8][64];
  const int t = threadIdx.x, lane = t & 63, w = t >> 6;
  const int wq = w & 1, sp = w >> 1;  // q-half, key-split
  // XCD swizzle: 768 blocks = 8 XCDs x (3 heads x 32 q-blocks)
  const int bid = blockIdx.x;
  const int xcd = bid & 7, idx = bid >> 3;
  const int bh = xcd * 3 + (idx >> 5);
  const int qb = idx & 31;
  const int bb = bh / 12, hh = bh % 12;
  const int qc = lane & 31, h = lane >> 5;
  const int q = qb * 64 + wq * 32 + qc;
  // Q B-fragments (pre-scaled by log2e/8): B[k][q], k = kc*16 + h*8 + j
  const unsigned short* qrow = qh + ((size_t)bh * 2048 + q) * 64;
  bf16x8 bq[4];
#pragma unroll
  for (int kc = 0; kc < 4; ++kc) bq[kc] = *(const bf16x8*)(qrow + kc * 16 + h * 8);
  const unsigned int* mrow = mp + ((size_t)bb * 2048 + q) * 64 + sp * 16;
  const unsigned short* kgb = kh + (size_t)bh * 2048 * 64;
  const unsigned short* vgb = vh + (size_t)bh * 64 * 2048;  // V^T: [64][2048]
  f32x16 acc0 = {}, acc1 = {};
  float l_run = 0.f;
  float m_run = -1e30f;
  const int KT0 = sp * 512;
  const int krow = lane >> 3, ksch = (lane & 7) ^ (lane >> 3);        // K staging
  const int vrow = lane >> 2, vsch = (lane & 3) ^ ((lane >> 3) & 3);  // V staging
  auto ISSUE = [&](int it2, int b2) {
    const int KT = KT0 + it2 * 32;
    unsigned short* kd = &lds.st.K[b2][sp][0][0];
    unsigned short* vd = &lds.st.V[b2][sp][0][0];
#pragma unroll
    for (int c2 = 0; c2 < 2; ++c2) {
      const int c = 2 * wq + c2;
      gll16(kgb + (size_t)(KT + c * 8 + krow) * 64 + ksch * 8, kd + c * 512);
    }
#pragma unroll
    for (int c2 = 0; c2 < 2; ++c2) {
      const int c = 2 * wq + c2;
      gll16(vgb + (size_t)(c * 16 + vrow) * 2048 + KT + vsch * 8, vd + c * 512);
    }
  };
  ISSUE(0, 0);
#pragma unroll 2
  for (int it = 0; it < 16; ++it) {
    const int b = it & 1;
    asm volatile("s_waitcnt vmcnt(0)" ::: "memory");
    __syncthreads();
    if (it < 15) ISSUE(it + 1, b ^ 1);
    const unsigned int m32 = mrow[it];
    // ---- K A-frags (swizzled ds_read) ----
    bf16x8 ka[4];
#pragma unroll
    for (int kc = 0; kc < 4; ++kc)
      ka[kc] = *(const bf16x8*)&lds.st.K[b][sp][qc][((kc * 2 + h) ^ (qc & 7)) * 8];
    f32x16 sc = {};
    __builtin_amdgcn_s_setprio(1);
#pragma unroll
    for (int kc = 0; kc < 4; ++kc)
      sc = __builtin_amdgcn_mfma_f32_32x32x16_bf16(ka[kc], bq[kc], sc, 0, 0, 0);
    __builtin_amdgcn_s_setprio(0);
    // ---- V A-frags (latency hidden under softmax) ----
    bf16x8 va0[2], va1[2];
#pragma unroll
    for (int ks = 0; ks < 2; ++ks) {
      const int cs = ((ks * 2 + h) ^ ((qc >> 1) & 3)) * 8;
      va0[ks] = *(const bf16x8*)&lds.st.V[b][sp][qc][cs];
      va1[ks] = *(const bf16x8*)&lds.st.V[b][sp][32 + qc][cs];
    }
    // ---- mask (key bit = (r&3)+8*(r>>2)+4h) ----
    const unsigned int wsh = m32 >> (4 * h);
#pragma unroll
    for (int r = 0; r < 16; ++r) {
      const int sh = (r & 3) + 8 * (r >> 2);
      sc[r] = ((wsh >> sh) & 1u) ? sc[r] : -3.0e38f;
    }
    // ---- tile max (balanced tree) ----
    float mA0 = fmaxf(fmaxf(sc[0], sc[4]), fmaxf(sc[8], sc[12]));
    float mA1 = fmaxf(fmaxf(sc[1], sc[5]), fmaxf(sc[9], sc[13]));
    float mA2 = fmaxf(fmaxf(sc[2], sc[6]), fmaxf(sc[10], sc[14]));
    float mA3 = fmaxf(fmaxf(sc[3], sc[7]), fmaxf(sc[11], sc[15]));
    float m1 = fmaxf(fmaxf(mA0, mA1), fmaxf(mA2, mA3));
    float tmax = fmaxf(m1, __shfl_xor(m1, 32, 64));
    // ---- T13 defer-rescale (log2 domain) ----
    if (__any(tmax > m_run + 8.0f)) {
      float mnew = fmaxf(m_run, tmax);
      float scl = exp2f(m_run - mnew);
      m_run = mnew;
      l_run *= scl;
#pragma unroll
      for (int e = 0; e < 16; ++e) { acc0[e] *= scl; acc1[e] *= scl; }
    }
    // ---- p = exp2(s - m), sum tree ----
#pragma unroll
    for (int r = 0; r < 16; ++r) sc[r] = exp2f(sc[r] - m_run);
    float sA0 = (sc[0] + sc[4]) + (sc[8] + sc[12]);
    float sA1 = (sc[1] + sc[5]) + (sc[9] + sc[13]);
    float sA2 = (sc[2] + sc[6]) + (sc[10] + sc[14]);
    float sA3 = (sc[3] + sc[7]) + (sc[11] + sc[15]);
    float s1 = (sA0 + sA1) + (sA2 + sA3);
    l_run += s1 + __shfl_xor(s1, 32, 64);
    // ---- PV: O^T += V^T . P^T (cvt_pk + permlane32_swap redistribution) ----
    __builtin_amdgcn_s_setprio(1);
#define PVQ(P, OFF, A0, A1) { \
    unsigned int a0 = cvtpk(P[OFF + 0], P[OFF + 1]), a1 = cvtpk(P[OFF + 2], P[OFF + 3]); \
    unsigned int b0 = cvtpk(P[OFF + 4], P[OFF + 5]), b1 = cvtpk(P[OFF + 6], P[OFF + 7]); \
    asm("v_permlane32_swap_b32 %0, %1" : "+v"(a0), "+v"(b0)); \
    asm("v_permlane32_swap_b32 %0, %1" : "+v"(a1), "+v"(b1)); \
    union { unsigned int u[4]; bf16x8 v; } bfu; \
    bfu.u[0] = a0; bfu.u[1] = a1; bfu.u[2] = b0; bfu.u[3] = b1; \
    acc0 = __builtin_amdgcn_mfma_f32_32x32x16_bf16(A0, bfu.v, acc0, 0, 0, 0); \
    acc1 = __builtin_amdgcn_mfma_f32_32x32x16_bf16(A1, bfu.v, acc1, 0, 0, 0); }
    PVQ(sc, 0, va0[0], va1[0]);
    PVQ(sc, 8, va0[1], va1[1]);
#undef PVQ
    __builtin_amdgcn_s_setprio(0);
  }
  __syncthreads();  // staging reads done before merge overlay writes
  // ---- merge 4 split partials through LDS ----
  Sm[w][lane] = m_run;
  Sl[w][lane] = l_run;
#pragma unroll
  for (int e = 0; e < 16; ++e) lds.M[w][e][lane] = acc0[e];
#pragma unroll
  for (int e = 0; e < 16; ++e) lds.M[w][16 + e][lane] = acc1[e];
  __syncthreads();
  float pm0 = Sm[wq][lane],     pm1 = Sm[2 + wq][lane];
  float pm2 = Sm[4 + wq][lane], pm3 = Sm[6 + wq][lane];
  float M = fmaxf(fmaxf(pm0, pm1), fmaxf(pm2, pm3));
  float w0 = exp2f(pm0 - M), w1 = exp2f(pm1 - M), w2 = exp2f(pm2 - M), w3 = exp2f(pm3 - M);
  float L = Sl[wq][lane] * w0 + Sl[2 + wq][lane] * w1 +
            Sl[4 + wq][lane] * w2 + Sl[6 + wq][lane] * w3;
  float inv = (L > 0.f) ? 1.0f / L : 0.f;
  unsigned short* orow = ao + ((size_t)bb * 2048 + q) * 768 + hh * 64;
#pragma unroll
  for (int g = 0; g < 2; ++g) {
    const int e0 = sp * 8 + g * 4;
    const int base = (e0 >= 16) ? 32 : 0;
    const int er0 = e0 & 15;
    const int d0 = base + 8 * (er0 >> 2) + 4 * h;
    u16x4 pk4;
#pragma unroll
    for (int j = 0; j < 4; ++j) {
      float v = (lds.M[wq][e0 + j][lane] * w0 + lds.M[2 + wq][e0 + j][lane] * w1 +
                 lds.M[4 + wq][e0 + j][lane] * w2 + lds.M[6 + wq][e0 + j][lane] * w3) * inv;
      pk4[j] = f2bf(v);
    }
    *(u16x4*)&orow[d0] = pk4;
  }
}

extern "C" void kernel_launch(void* const* d_in, const int* in_sizes, int n_in,
                              void* d_out, int out_size, void* d_ws, size_t ws_size,
                              hipStream_t stream) {
  const float* Q  = (const float*)d_in[0];
  const float* K  = (const float*)d_in[1];
  const float* V  = (const float*)d_in[2];
  const int*   mask = (const int*)d_in[3];
  const float* WQ = (const float*)d_in[4];
  const float* WK = (const float*)d_in[5];
  const float* WV = (const float*)d_in[6];
  const float* WO = (const float*)d_in[7];
  float* out = (float*)d_out;
  char* ws = (char*)d_ws;

  const size_t NEED = 43515904ull;
  if (ws_size >= NEED) {
    unsigned short* qh  = (unsigned short*)(ws + 0);
    unsigned short* kh  = (unsigned short*)(ws + 6291456);
    unsigned short* vh  = (unsigned short*)(ws + 12582912);
    unsigned int*   mp  = (unsigned int*)(ws + 18874368);
    unsigned short* Qb  = (unsigned short*)(ws + 19922944);  // aliased by ao after proj
    unsigned short* ao  = Qb;
    unsigned short* Kb  = (unsigned short*)(ws + 26214400);
    unsigned short* Vb  = (unsigned short*)(ws + 32505856);
    unsigned short* Wqb = (unsigned short*)(ws + 38797312);
    unsigned short* Wkb = (unsigned short*)(ws + 39976960);
    unsigned short* Wvb = (unsigned short*)(ws + 41156608);
    unsigned short* Wob = (unsigned short*)(ws + 42336256);
    prep_kernel<<<dim3(3904), 256, 0, stream>>>(mask, mp, Q, K, V, WQ, WK, WV, WO,
                                                Qb, Kb, Vb, Wqb, Wkb, Wvb, Wob);
    proj_b16<<<dim3(6, 32, 3), 256, 0, stream>>>(Qb, Kb, Vb, Wqb, Wkb, Wvb, qh, kh, vh);
    attn_kernel<<<dim3(768), 512, 0, stream>>>(qh, kh, vh, mp, ao);
    out_b16<<<dim3(6, 32), 256, 0, stream>>>(ao, Wob, out);
  } else {
    unsigned short* qh = (unsigned short*)(ws + 0);
    unsigned short* kh = (unsigned short*)(ws + 6291456);
    unsigned short* vh = (unsigned short*)(ws + 12582912);
    unsigned short* ao = (unsigned short*)(ws + 18874368);
    unsigned int*   mp = (unsigned int*)(ws + 25165824);
    maskpack_kernel<<<dim3(2048), 256, 0, stream>>>(mask, mp, 2 * 2048 * 2048);
    proj_gemm<<<dim3(6, 32, 3), 256, 0, stream>>>(Q, K, V, WQ, WK, WV, qh, kh, vh);
    attn_kernel<<<dim3(768), 512, 0, stream>>>(qh, kh, vh, mp, ao);
    out_gemm<<<dim3(6, 32), 256, 0, stream>>>(ao, WO, out);
  }
}